// Round 17
// baseline (60.225 us; speedup 1.0000x reference)
//
#include <hip/hip_runtime.h>
#include <hip/hip_bf16.h>
#include <cstddef>

typedef __attribute__((ext_vector_type(8))) __bf16 bf16x8;
typedef __attribute__((ext_vector_type(4))) float f32x4;
typedef unsigned long long ull_t;

static __device__ __forceinline__ unsigned short f2bf(float f) {
    __bf16 h = (__bf16)f;
    return __builtin_bit_cast(unsigned short, h);
}

// ---------------- prep (merged, coalesced): Wqkv + WpEff in MFMA-fragment order ----------
__global__ void prep_weights(const float* __restrict__ Wq, const float* __restrict__ Wk,
                             const float* __restrict__ Wv, const float* __restrict__ Wp,
                             unsigned short* __restrict__ Wfrag,
                             unsigned short* __restrict__ WpFrag) {
    if (blockIdx.x < 96) {
        int gid = blockIdx.x * 256 + threadIdx.x;    // 0..24575
        int m = gid >> 13;                           // 0..2
        int rem = gid & 8191;
        int khi = rem >> 6;                          // 0..127
        int lcol = rem & 63;                         // 0..63
        const float* W = (m == 0) ? Wq : (m == 1) ? Wk : Wv;
        bf16x8 v;
#pragma unroll
        for (int j = 0; j < 8; ++j)
            v[j] = (__bf16)W[(khi * 8 + j) * 64 + lcol];
        int CB = m * 4 + (lcol >> 4);
        int S = khi >> 2;
        int lane = ((khi & 3) << 4) | (lcol & 15);
        *(bf16x8*)(Wfrag + ((size_t)(CB * 32 + S) * 512 + lane * 8)) = v;
    } else {
        int gid = (blockIdx.x - 96) * 256 + threadIdx.x;    // 0..8191
        int h = gid >> 7;                                   // 0..63
        int cc = gid & 127;                                 // col chunk
        float s0 = 0.f, s1 = 0.f, s2 = 0.f, s3 = 0.f, s4 = 0.f, s5 = 0.f, s6 = 0.f, s7 = 0.f;
#pragma unroll
        for (int j16 = 0; j16 < 16; ++j16) {
            const float* row = Wp + (size_t)(j16 * 64 + h) * 1024 + cc * 8;
            float4 a = *(const float4*)(row);
            float4 b = *(const float4*)(row + 4);
            s0 += a.x; s1 += a.y; s2 += a.z; s3 += a.w;
            s4 += b.x; s5 += b.y; s6 += b.z; s7 += b.w;
        }
        float sum[8] = {s0, s1, s2, s3, s4, s5, s6, s7};
        int sp = h >> 5, hi = (h >> 3) & 3, j = h & 7;
#pragma unroll
        for (int q = 0; q < 8; ++q) {
            int col = cc * 8 + q;
            int lane = (hi << 4) | (col & 15);
            int CB = col >> 4;
            WpFrag[(size_t)(CB * 2 + sp) * 512 + lane * 8 + j] = f2bf(sum[q]);
        }
    }
}

// ---------------- QKV GEMM v11 (R16 best): XCD-aligned producer mapping ------------------
__global__ __launch_bounds__(256) void qkv_gemm(const float* __restrict__ x,
                                                const unsigned short* __restrict__ Wfrag,
                                                unsigned short* __restrict__ qs,
                                                unsigned short* __restrict__ ks,
                                                unsigned short* __restrict__ vT) {
    __shared__ __align__(16) unsigned short xl[2][32 * 128];   // 16 KB, XOR-swizzled rows

    const int tid = threadIdx.x;
    const int lane = tid & 63;
    const int w = tid >> 6;
    const int g = lane >> 4, c = lane & 15;
    const int xcd8 = blockIdx.x & 7;
    const int seq = blockIdx.x >> 3;      // 0..63
    const int row0 = (2 * xcd8 + (seq >> 5)) * 1024 + (seq & 31) * 32;

    const int srow = tid >> 3;            // 0..31
    const int scolf = (tid & 7) * 16;     // float col 0,16,...,112
    const float* xsrc = x + (size_t)(row0 + srow) * 1024 + scolf;
    const int sdst0 = srow * 256 + ((scolf * 2) ^ ((srow & 7) << 4));
    const int sdst1 = srow * 256 + ((scolf * 2 + 16) ^ ((srow & 7) << 4));

    const unsigned short* wbase = Wfrag + (size_t)(w * 3) * 32 * 512 + lane * 8;

    f32x4 acc[2][3];
#pragma unroll
    for (int mr = 0; mr < 2; ++mr)
#pragma unroll
        for (int cb = 0; cb < 3; ++cb) acc[mr][cb] = (f32x4){0.f, 0.f, 0.f, 0.f};

    float4 pre0[4], pre1[4];              // two in-flight x-chunk register sets
#pragma unroll
    for (int i = 0; i < 4; ++i) pre0[i] = *(const float4*)(xsrc + i * 4);
#pragma unroll
    for (int i = 0; i < 4; ++i) pre1[i] = *(const float4*)(xsrc + 128 + i * 4);

    bf16x8 bP[3][6];                      // B pair triple-buffer (i = sl*3+cb)
#pragma unroll
    for (int pp = 0; pp < 2; ++pp) {
#pragma unroll
        for (int i = 0; i < 6; ++i) {
            int SB = pp * 2 + (i / 3);
            int cb = i % 3;
            bP[pp][i] = *(const bf16x8*)(wbase + ((size_t)(cb * 32 + SB) * 512));
        }
    }

    {   // write x chunk 0 to LDS[0]
        bf16x8 v0, v1;
#pragma unroll
        for (int j = 0; j < 4; ++j) { v0[j] = (__bf16)pre0[0][j]; v0[4 + j] = (__bf16)pre0[1][j]; }
#pragma unroll
        for (int j = 0; j < 4; ++j) { v1[j] = (__bf16)pre0[2][j]; v1[4 + j] = (__bf16)pre0[3][j]; }
        *(bf16x8*)((char*)xl[0] + sdst0) = v0;
        *(bf16x8*)((char*)xl[0] + sdst1) = v1;
    }
    __syncthreads();

#pragma unroll
    for (int p = 0; p < 16; ++p) {        // p = k-step pair; chunk t = p>>1 in LDS[t&1]
        const int t = p >> 1;
        if ((p & 1) == 0 && t + 2 < 8) {  // issue x chunk t+2 into set (t&1)
            if ((t & 1) == 0) {
#pragma unroll
                for (int i = 0; i < 4; ++i) pre0[i] = *(const float4*)(xsrc + (t + 2) * 128 + i * 4);
            } else {
#pragma unroll
                for (int i = 0; i < 4; ++i) pre1[i] = *(const float4*)(xsrc + (t + 2) * 128 + i * 4);
            }
        }
        if (p + 2 < 16) {                 // issue B pair p+2 (distance-2)
#pragma unroll
            for (int i = 0; i < 6; ++i) {
                int SB = (p + 2) * 2 + (i / 3);
                int cb = i % 3;
                bP[(p + 2) % 3][i] = *(const bf16x8*)(wbase + ((size_t)(cb * 32 + SB) * 512));
            }
        }
#pragma unroll
        for (int sl = 0; sl < 2; ++sl) {
            int s = (p & 1) * 2 + sl;
            bf16x8 af[2];
#pragma unroll
            for (int mr = 0; mr < 2; ++mr)
                af[mr] = *(const bf16x8*)((char*)xl[t & 1] + (mr * 16 + c) * 256 +
                                          ((s * 64 + g * 16) ^ ((c & 7) << 4)));
#pragma unroll
            for (int cb = 0; cb < 3; ++cb) {
                acc[0][cb] = __builtin_amdgcn_mfma_f32_16x16x32_bf16(af[0], bP[p % 3][sl * 3 + cb], acc[0][cb], 0, 0, 0);
                acc[1][cb] = __builtin_amdgcn_mfma_f32_16x16x32_bf16(af[1], bP[p % 3][sl * 3 + cb], acc[1][cb], 0, 0, 0);
            }
        }
        if (p & 1) {
            if (t < 7) {                  // write x chunk t+1 from set (t+1)&1
                bf16x8 v0, v1;
                if ((t & 1) == 0) {
#pragma unroll
                    for (int j = 0; j < 4; ++j) { v0[j] = (__bf16)pre1[0][j]; v0[4 + j] = (__bf16)pre1[1][j]; }
#pragma unroll
                    for (int j = 0; j < 4; ++j) { v1[j] = (__bf16)pre1[2][j]; v1[4 + j] = (__bf16)pre1[3][j]; }
                    *(bf16x8*)((char*)xl[1] + sdst0) = v0;
                    *(bf16x8*)((char*)xl[1] + sdst1) = v1;
                } else {
#pragma unroll
                    for (int j = 0; j < 4; ++j) { v0[j] = (__bf16)pre0[0][j]; v0[4 + j] = (__bf16)pre0[1][j]; }
#pragma unroll
                    for (int j = 0; j < 4; ++j) { v1[j] = (__bf16)pre0[2][j]; v1[4 + j] = (__bf16)pre0[3][j]; }
                    *(bf16x8*)((char*)xl[0] + sdst0) = v0;
                    *(bf16x8*)((char*)xl[0] + sdst1) = v1;
                }
            }
            __syncthreads();
        }
    }

    const float QSCALE = 0.125f * 1.44269504088896340736f;  // (1/sqrt(64)) * log2(e)
#pragma unroll
    for (int mr = 0; mr < 2; ++mr) {
#pragma unroll
        for (int cb = 0; cb < 3; ++cb) {
            int col = w * 48 + cb * 16 + c;
            int rowb = row0 + mr * 16 + g * 4;
            if (col < 64) {
#pragma unroll
                for (int r = 0; r < 4; ++r)
                    qs[(size_t)(rowb + r) * 64 + col] = f2bf(acc[mr][cb][r] * QSCALE);
            } else if (col < 128) {
#pragma unroll
                for (int r = 0; r < 4; ++r)
                    ks[(size_t)(rowb + r) * 64 + (col - 64)] = f2bf(acc[mr][cb][r]);
            } else {
                int h = col - 128;
                int bb = rowb >> 10, trow = rowb & 1023;
                ull_t dv =
                    (ull_t)f2bf(acc[mr][cb][0]) |
                    ((ull_t)f2bf(acc[mr][cb][1]) << 16) |
                    ((ull_t)f2bf(acc[mr][cb][2]) << 32) |
                    ((ull_t)f2bf(acc[mr][cb][3]) << 48);
                *(ull_t*)(vT + (size_t)bb * 65536 + (size_t)h * 1024 + trow) = dv;
            }
        }
    }
}

// ---------------- fused attention+projection v7: R16 KV + swapped proj (float4 stores) ---
__global__ __launch_bounds__(256) void attn_proj(const unsigned short* __restrict__ qs,
                                                 const unsigned short* __restrict__ ks,
                                                 const unsigned short* __restrict__ vT,
                                                 const unsigned short* __restrict__ WpFrag,
                                                 const float* __restrict__ bp,
                                                 float* __restrict__ out) {
    __shared__ unsigned short Plds[4][16 * 40];
    __shared__ float oL[2][1024];                    // half-1 partial o per tile
    __shared__ float pL[2][256];                     // half-1 partial psum per tile
    __shared__ __align__(16) unsigned short hl[2][16 * 64];   // normalized ho tiles, swizzled

    const int tid = threadIdx.x;
    const int lane = tid & 63;
    const int wid = tid >> 6;
    const int tslot = wid >> 1;       // tile slot 0/1
    const int half = wid & 1;
    const int g = lane >> 4, c = lane & 15;

    const int xcd = blockIdx.x & 7;
    const int k8 = blockIdx.x >> 3;              // 0..63
    const int bb = 2 * xcd + tslot;              // XCD-local batch
    const int qidx = 63 - k8;                    // biggest tiles first per XCD
    const int qr0 = qidx * 16;
    const int qend = qr0 + 16;
    const int nc = (qidx >> 1) + 1;              // KV chunks of 32
    const int c0 = half ? (nc >> 1) : 0;
    const int c1 = half ? nc : (nc >> 1);

    const unsigned short* qbase = qs + ((size_t)bb * 1024 + qr0 + c) * 64 + g * 8;
    bf16x8 aq0 = *(const bf16x8*)(qbase);
    bf16x8 aq1 = *(const bf16x8*)(qbase + 32);

    const unsigned short* kB = ks + (size_t)bb * 1024 * 64;
    const unsigned short* vB = vT + (size_t)bb * 64 * 1024;

    f32x4 o[4];
#pragma unroll
    for (int i = 0; i < 4; ++i) o[i] = (f32x4){0.f, 0.f, 0.f, 0.f};
    float psum[4] = {0.f, 0.f, 0.f, 0.f};
    const f32x4 zero = {0.f, 0.f, 0.f, 0.f};

    bf16x8 kc0, kc1, kc2, kc3, vc0, vc1, vc2, vc3;
    if (c0 < c1) {
        const unsigned short* kp = kB + (size_t)(c0 * 32 + c) * 64 + g * 8;
        kc0 = *(const bf16x8*)(kp);
        kc1 = *(const bf16x8*)(kp + 32);
        kc2 = *(const bf16x8*)(kp + 16 * 64);
        kc3 = *(const bf16x8*)(kp + 16 * 64 + 32);
        const unsigned short* vp = vB + (size_t)c * 1024 + c0 * 32 + g * 8;
        vc0 = *(const bf16x8*)(vp);
        vc1 = *(const bf16x8*)(vp + 16 * 1024);
        vc2 = *(const bf16x8*)(vp + 32 * 1024);
        vc3 = *(const bf16x8*)(vp + 48 * 1024);
    }

    for (int ci = c0; ci < c1; ++ci) {
        const int j0 = ci * 32;
        const bool full = (j0 + 16 < qend);
        f32x4 s0 = __builtin_amdgcn_mfma_f32_16x16x32_bf16(aq0, kc0, zero, 0, 0, 0);
        s0 = __builtin_amdgcn_mfma_f32_16x16x32_bf16(aq1, kc1, s0, 0, 0, 0);
        f32x4 s1 = zero;
        if (full) {
            s1 = __builtin_amdgcn_mfma_f32_16x16x32_bf16(aq0, kc2, zero, 0, 0, 0);
            s1 = __builtin_amdgcn_mfma_f32_16x16x32_bf16(aq1, kc3, s1, 0, 0, 0);
        }

        bf16x8 kn0, kn1, kn2, kn3, vn0, vn1, vn2, vn3;
        if (ci + 1 < c1) {
            const int jn = (ci + 1) * 32;
            const unsigned short* kp = kB + (size_t)(jn + c) * 64 + g * 8;
            kn0 = *(const bf16x8*)(kp);
            kn1 = *(const bf16x8*)(kp + 32);
            kn2 = *(const bf16x8*)(kp + 16 * 64);
            kn3 = *(const bf16x8*)(kp + 16 * 64 + 32);
            const unsigned short* vp = vB + (size_t)c * 1024 + jn + g * 8;
            vn0 = *(const bf16x8*)(vp);
            vn1 = *(const bf16x8*)(vp + 16 * 1024);
            vn2 = *(const bf16x8*)(vp + 32 * 1024);
            vn3 = *(const bf16x8*)(vp + 48 * 1024);
        }

#pragma unroll
        for (int r = 0; r < 4; ++r) {
            int t = qr0 + g * 4 + r;
            float e0 = (j0 + c > t) ? 0.f : exp2f(s0[r]);
            float e1 = (!full || j0 + 16 + c > t) ? 0.f : exp2f(s1[r]);
            psum[r] += e0 + e1;
            Plds[wid][(g * 4 + r) * 40 + c]      = f2bf(e0);
            Plds[wid][(g * 4 + r) * 40 + 16 + c] = f2bf(e1);
        }
        bf16x8 pa = *(const bf16x8*)(&Plds[wid][c * 40 + g * 8]);
        o[0] = __builtin_amdgcn_mfma_f32_16x16x32_bf16(pa, vc0, o[0], 0, 0, 0);
        o[1] = __builtin_amdgcn_mfma_f32_16x16x32_bf16(pa, vc1, o[1], 0, 0, 0);
        o[2] = __builtin_amdgcn_mfma_f32_16x16x32_bf16(pa, vc2, o[2], 0, 0, 0);
        o[3] = __builtin_amdgcn_mfma_f32_16x16x32_bf16(pa, vc3, o[3], 0, 0, 0);

        kc0 = kn0; kc1 = kn1; kc2 = kn2; kc3 = kn3;
        vc0 = vn0; vc1 = vn1; vc2 = vn2; vc3 = vn3;
    }

    if (half == 1) {
#pragma unroll
        for (int hb = 0; hb < 4; ++hb)
            *(f32x4*)&oL[tslot][(hb * 64 + lane) * 4] = o[hb];
        f32x4 pv = {psum[0], psum[1], psum[2], psum[3]};
        *(f32x4*)&pL[tslot][lane * 4] = pv;
    }
    __syncthreads();
    if (half == 0) {
        f32x4 pv = *(const f32x4*)&pL[tslot][lane * 4];
        float inv[4];
#pragma unroll
        for (int r = 0; r < 4; ++r) {
            float ps = psum[r] + pv[r];
            ps += __shfl_xor(ps, 1);
            ps += __shfl_xor(ps, 2);
            ps += __shfl_xor(ps, 4);
            ps += __shfl_xor(ps, 8);
            inv[r] = 1.f / ps;
        }
#pragma unroll
        for (int hb = 0; hb < 4; ++hb) {
            f32x4 po = *(const f32x4*)&oL[tslot][(hb * 64 + lane) * 4];
#pragma unroll
            for (int r = 0; r < 4; ++r) {
                int row = g * 4 + r;
                int colb = (hb * 16 + c) * 2;
                *(unsigned short*)((char*)hl[tslot] + row * 128 + (colb ^ ((row & 7) << 4))) =
                    f2bf((o[hb][r] + po[r]) * inv[r]);
            }
        }
    }
    __syncthreads();

    // projection (SWAPPED operands): A = WpFrag, B = ho tile -> lane holds 4 consecutive
    // out-cols of one token row -> ONE float4 store per tile per col-block (was 4 scalar).
    bf16x8 h0t0 = *(const bf16x8*)((char*)hl[0] + c * 128 + ((g * 16) ^ ((c & 7) << 4)));
    bf16x8 h1t0 = *(const bf16x8*)((char*)hl[0] + c * 128 + ((64 + g * 16) ^ ((c & 7) << 4)));
    bf16x8 h0t1 = *(const bf16x8*)((char*)hl[1] + c * 128 + ((g * 16) ^ ((c & 7) << 4)));
    bf16x8 h1t1 = *(const bf16x8*)((char*)hl[1] + c * 128 + ((64 + g * 16) ^ ((c & 7) << 4)));
    const int b0 = 2 * xcd;
    const int b1 = 2 * xcd + 1;
    const size_t ob0 = ((size_t)b0 * 1024 + qr0) * 1024;
    const size_t ob1 = ((size_t)b1 * 1024 + qr0) * 1024;
#pragma unroll
    for (int cb = 0; cb < 16; ++cb) {
        int CB = wid * 16 + cb;
        bf16x8 wb0 = *(const bf16x8*)(WpFrag + (size_t)(CB * 2 + 0) * 512 + lane * 8);
        bf16x8 wb1 = *(const bf16x8*)(WpFrag + (size_t)(CB * 2 + 1) * 512 + lane * 8);
        f32x4 acc0 = __builtin_amdgcn_mfma_f32_16x16x32_bf16(wb0, h0t0, zero, 0, 0, 0);
        acc0 = __builtin_amdgcn_mfma_f32_16x16x32_bf16(wb1, h1t0, acc0, 0, 0, 0);
        f32x4 acc1 = __builtin_amdgcn_mfma_f32_16x16x32_bf16(wb0, h0t1, zero, 0, 0, 0);
        acc1 = __builtin_amdgcn_mfma_f32_16x16x32_bf16(wb1, h1t1, acc1, 0, 0, 0);
        int colb = CB * 16 + g * 4;
        float4 bias = *(const float4*)(bp + colb);
        float4 r0 = {acc0[0] + bias.x, acc0[1] + bias.y, acc0[2] + bias.z, acc0[3] + bias.w};
        float4 r1 = {acc1[0] + bias.x, acc1[1] + bias.y, acc1[2] + bias.z, acc1[3] + bias.w};
        *(float4*)(out + ob0 + (size_t)c * 1024 + colb) = r0;
        *(float4*)(out + ob1 + (size_t)c * 1024 + colb) = r1;
    }
}

extern "C" void kernel_launch(void* const* d_in, const int* in_sizes, int n_in,
                              void* d_out, int out_size, void* d_ws, size_t ws_size,
                              hipStream_t stream) {
    (void)in_sizes; (void)n_in; (void)out_size; (void)ws_size;
    const float* x  = (const float*)d_in[0];
    const float* Wq = (const float*)d_in[1];
    const float* Wk = (const float*)d_in[2];
    const float* Wv = (const float*)d_in[3];
    const float* Wp = (const float*)d_in[4];
    const float* bp = (const float*)d_in[5];
    float* out = (float*)d_out;

    const size_t NTOK = 16 * 1024;            // B*T
    unsigned short* ws = (unsigned short*)d_ws;
    unsigned short* qs     = ws;                       // [16384][64]
    unsigned short* ks     = qs + NTOK * 64;           // [16384][64]
    unsigned short* vT     = ks + NTOK * 64;           // [16][64][1024]
    unsigned short* Wfrag  = vT + NTOK * 64;           // [12][32][512]
    unsigned short* WpFrag = Wfrag + 192 * 1024;       // [64][2][512]

    prep_weights<<<128, 256, 0, stream>>>(Wq, Wk, Wv, Wp, Wfrag, WpFrag);
    qkv_gemm<<<512, 256, 0, stream>>>(x, Wfrag, qs, ks, vT);
    attn_proj<<<512, 256, 0, stream>>>(qs, ks, vT, WpFrag, bp, out);
}

// Round 18
// 56.136 us; speedup vs baseline: 1.0728x; 1.0728x over previous
//
#include <hip/hip_runtime.h>
#include <hip/hip_bf16.h>
#include <cstddef>

typedef __attribute__((ext_vector_type(8))) __bf16 bf16x8;
typedef __attribute__((ext_vector_type(4))) float f32x4;
typedef unsigned long long ull_t;

static __device__ __forceinline__ unsigned short f2bf(float f) {
    __bf16 h = (__bf16)f;
    return __builtin_bit_cast(unsigned short, h);
}

// ---------------- prep (merged, coalesced): Wqkv + WpEff in MFMA-fragment order ----------
__global__ void prep_weights(const float* __restrict__ Wq, const float* __restrict__ Wk,
                             const float* __restrict__ Wv, const float* __restrict__ Wp,
                             unsigned short* __restrict__ Wfrag,
                             unsigned short* __restrict__ WpFrag) {
    if (blockIdx.x < 96) {
        int gid = blockIdx.x * 256 + threadIdx.x;    // 0..24575
        int m = gid >> 13;                           // 0..2
        int rem = gid & 8191;
        int khi = rem >> 6;                          // 0..127
        int lcol = rem & 63;                         // 0..63
        const float* W = (m == 0) ? Wq : (m == 1) ? Wk : Wv;
        bf16x8 v;
#pragma unroll
        for (int j = 0; j < 8; ++j)
            v[j] = (__bf16)W[(khi * 8 + j) * 64 + lcol];
        int CB = m * 4 + (lcol >> 4);
        int S = khi >> 2;
        int lane = ((khi & 3) << 4) | (lcol & 15);
        *(bf16x8*)(Wfrag + ((size_t)(CB * 32 + S) * 512 + lane * 8)) = v;
    } else {
        int gid = (blockIdx.x - 96) * 256 + threadIdx.x;    // 0..8191
        int h = gid >> 7;                                   // 0..63
        int cc = gid & 127;                                 // col chunk
        float s0 = 0.f, s1 = 0.f, s2 = 0.f, s3 = 0.f, s4 = 0.f, s5 = 0.f, s6 = 0.f, s7 = 0.f;
#pragma unroll
        for (int j16 = 0; j16 < 16; ++j16) {
            const float* row = Wp + (size_t)(j16 * 64 + h) * 1024 + cc * 8;
            float4 a = *(const float4*)(row);
            float4 b = *(const float4*)(row + 4);
            s0 += a.x; s1 += a.y; s2 += a.z; s3 += a.w;
            s4 += b.x; s5 += b.y; s6 += b.z; s7 += b.w;
        }
        float sum[8] = {s0, s1, s2, s3, s4, s5, s6, s7};
        int sp = h >> 5, hi = (h >> 3) & 3, j = h & 7;
#pragma unroll
        for (int q = 0; q < 8; ++q) {
            int col = cc * 8 + q;
            int lane = (hi << 4) | (col & 15);
            int CB = col >> 4;
            WpFrag[(size_t)(CB * 2 + sp) * 512 + lane * 8 + j] = f2bf(sum[q]);
        }
    }
}

// ---------------- QKV GEMM v11 (R16 best): XCD-aligned producer mapping ------------------
__global__ __launch_bounds__(256) void qkv_gemm(const float* __restrict__ x,
                                                const unsigned short* __restrict__ Wfrag,
                                                unsigned short* __restrict__ qs,
                                                unsigned short* __restrict__ ks,
                                                unsigned short* __restrict__ vT) {
    __shared__ __align__(16) unsigned short xl[2][32 * 128];   // 16 KB, XOR-swizzled rows

    const int tid = threadIdx.x;
    const int lane = tid & 63;
    const int w = tid >> 6;
    const int g = lane >> 4, c = lane & 15;
    const int xcd8 = blockIdx.x & 7;
    const int seq = blockIdx.x >> 3;      // 0..63
    const int row0 = (2 * xcd8 + (seq >> 5)) * 1024 + (seq & 31) * 32;

    const int srow = tid >> 3;            // 0..31
    const int scolf = (tid & 7) * 16;     // float col 0,16,...,112
    const float* xsrc = x + (size_t)(row0 + srow) * 1024 + scolf;
    const int sdst0 = srow * 256 + ((scolf * 2) ^ ((srow & 7) << 4));
    const int sdst1 = srow * 256 + ((scolf * 2 + 16) ^ ((srow & 7) << 4));

    const unsigned short* wbase = Wfrag + (size_t)(w * 3) * 32 * 512 + lane * 8;

    f32x4 acc[2][3];
#pragma unroll
    for (int mr = 0; mr < 2; ++mr)
#pragma unroll
        for (int cb = 0; cb < 3; ++cb) acc[mr][cb] = (f32x4){0.f, 0.f, 0.f, 0.f};

    float4 pre0[4], pre1[4];              // two in-flight x-chunk register sets
#pragma unroll
    for (int i = 0; i < 4; ++i) pre0[i] = *(const float4*)(xsrc + i * 4);
#pragma unroll
    for (int i = 0; i < 4; ++i) pre1[i] = *(const float4*)(xsrc + 128 + i * 4);

    bf16x8 bP[3][6];                      // B pair triple-buffer (i = sl*3+cb)
#pragma unroll
    for (int pp = 0; pp < 2; ++pp) {
#pragma unroll
        for (int i = 0; i < 6; ++i) {
            int SB = pp * 2 + (i / 3);
            int cb = i % 3;
            bP[pp][i] = *(const bf16x8*)(wbase + ((size_t)(cb * 32 + SB) * 512));
        }
    }

    {   // write x chunk 0 to LDS[0]
        bf16x8 v0, v1;
#pragma unroll
        for (int j = 0; j < 4; ++j) { v0[j] = (__bf16)pre0[0][j]; v0[4 + j] = (__bf16)pre0[1][j]; }
#pragma unroll
        for (int j = 0; j < 4; ++j) { v1[j] = (__bf16)pre0[2][j]; v1[4 + j] = (__bf16)pre0[3][j]; }
        *(bf16x8*)((char*)xl[0] + sdst0) = v0;
        *(bf16x8*)((char*)xl[0] + sdst1) = v1;
    }
    __syncthreads();

#pragma unroll
    for (int p = 0; p < 16; ++p) {        // p = k-step pair; chunk t = p>>1 in LDS[t&1]
        const int t = p >> 1;
        if ((p & 1) == 0 && t + 2 < 8) {  // issue x chunk t+2 into set (t&1)
            if ((t & 1) == 0) {
#pragma unroll
                for (int i = 0; i < 4; ++i) pre0[i] = *(const float4*)(xsrc + (t + 2) * 128 + i * 4);
            } else {
#pragma unroll
                for (int i = 0; i < 4; ++i) pre1[i] = *(const float4*)(xsrc + (t + 2) * 128 + i * 4);
            }
        }
        if (p + 2 < 16) {                 // issue B pair p+2 (distance-2)
#pragma unroll
            for (int i = 0; i < 6; ++i) {
                int SB = (p + 2) * 2 + (i / 3);
                int cb = i % 3;
                bP[(p + 2) % 3][i] = *(const bf16x8*)(wbase + ((size_t)(cb * 32 + SB) * 512));
            }
        }
#pragma unroll
        for (int sl = 0; sl < 2; ++sl) {
            int s = (p & 1) * 2 + sl;
            bf16x8 af[2];
#pragma unroll
            for (int mr = 0; mr < 2; ++mr)
                af[mr] = *(const bf16x8*)((char*)xl[t & 1] + (mr * 16 + c) * 256 +
                                          ((s * 64 + g * 16) ^ ((c & 7) << 4)));
#pragma unroll
            for (int cb = 0; cb < 3; ++cb) {
                acc[0][cb] = __builtin_amdgcn_mfma_f32_16x16x32_bf16(af[0], bP[p % 3][sl * 3 + cb], acc[0][cb], 0, 0, 0);
                acc[1][cb] = __builtin_amdgcn_mfma_f32_16x16x32_bf16(af[1], bP[p % 3][sl * 3 + cb], acc[1][cb], 0, 0, 0);
            }
        }
        if (p & 1) {
            if (t < 7) {                  // write x chunk t+1 from set (t+1)&1
                bf16x8 v0, v1;
                if ((t & 1) == 0) {
#pragma unroll
                    for (int j = 0; j < 4; ++j) { v0[j] = (__bf16)pre1[0][j]; v0[4 + j] = (__bf16)pre1[1][j]; }
#pragma unroll
                    for (int j = 0; j < 4; ++j) { v1[j] = (__bf16)pre1[2][j]; v1[4 + j] = (__bf16)pre1[3][j]; }
                    *(bf16x8*)((char*)xl[1] + sdst0) = v0;
                    *(bf16x8*)((char*)xl[1] + sdst1) = v1;
                } else {
#pragma unroll
                    for (int j = 0; j < 4; ++j) { v0[j] = (__bf16)pre0[0][j]; v0[4 + j] = (__bf16)pre0[1][j]; }
#pragma unroll
                    for (int j = 0; j < 4; ++j) { v1[j] = (__bf16)pre0[2][j]; v1[4 + j] = (__bf16)pre0[3][j]; }
                    *(bf16x8*)((char*)xl[0] + sdst0) = v0;
                    *(bf16x8*)((char*)xl[0] + sdst1) = v1;
                }
            }
            __syncthreads();
        }
    }

    const float QSCALE = 0.125f * 1.44269504088896340736f;  // (1/sqrt(64)) * log2(e)
#pragma unroll
    for (int mr = 0; mr < 2; ++mr) {
#pragma unroll
        for (int cb = 0; cb < 3; ++cb) {
            int col = w * 48 + cb * 16 + c;
            int rowb = row0 + mr * 16 + g * 4;
            if (col < 64) {
#pragma unroll
                for (int r = 0; r < 4; ++r)
                    qs[(size_t)(rowb + r) * 64 + col] = f2bf(acc[mr][cb][r] * QSCALE);
            } else if (col < 128) {
#pragma unroll
                for (int r = 0; r < 4; ++r)
                    ks[(size_t)(rowb + r) * 64 + (col - 64)] = f2bf(acc[mr][cb][r]);
            } else {
                int h = col - 128;
                int bb = rowb >> 10, trow = rowb & 1023;
                ull_t dv =
                    (ull_t)f2bf(acc[mr][cb][0]) |
                    ((ull_t)f2bf(acc[mr][cb][1]) << 16) |
                    ((ull_t)f2bf(acc[mr][cb][2]) << 32) |
                    ((ull_t)f2bf(acc[mr][cb][3]) << 48);
                *(ull_t*)(vT + (size_t)bb * 65536 + (size_t)h * 1024 + trow) = dv;
            }
        }
    }
}

// ---------------- fused attention+projection v8: 4 tiles/block, grid 256, 8 waves --------
// Per tile: proven 2-wave KV split + combine (R16 code). Block k pairs qidx {63-k, k}
// (balanced) x 2 XCD-local batches. Proj: WpFrag fragment loaded once serves 4 tiles
// (L2 traffic halved); unswapped scalar stores (proven).
__global__ __launch_bounds__(512) void attn_proj(const unsigned short* __restrict__ qs,
                                                 const unsigned short* __restrict__ ks,
                                                 const unsigned short* __restrict__ vT,
                                                 const unsigned short* __restrict__ WpFrag,
                                                 const float* __restrict__ bp,
                                                 float* __restrict__ out) {
    __shared__ unsigned short Plds[8][16 * 40];
    __shared__ float oL[4][1024];                    // half-1 partial o per tile
    __shared__ float pL[4][256];                     // half-1 partial psum per tile
    __shared__ __align__(16) unsigned short hl[4][16 * 64];   // normalized ho tiles, swizzled

    const int tid = threadIdx.x;
    const int lane = tid & 63;
    const int wid = tid >> 6;         // 0..7
    const int tslot = wid >> 1;       // tile slot 0..3
    const int half = wid & 1;
    const int g = lane >> 4, c = lane & 15;

    const int xcd = blockIdx.x & 7;
    const int k = blockIdx.x >> 3;               // 0..31
    const int bb = 2 * xcd + (tslot & 1);        // XCD-local batch
    const int qidx = (tslot >> 1) == 0 ? (63 - k) : k;   // big+small pairing
    const int qr0 = qidx * 16;
    const int qend = qr0 + 16;
    const int nc = (qidx >> 1) + 1;              // KV chunks of 32
    const int c0 = half ? (nc >> 1) : 0;
    const int c1 = half ? nc : (nc >> 1);

    const unsigned short* qbase = qs + ((size_t)bb * 1024 + qr0 + c) * 64 + g * 8;
    bf16x8 aq0 = *(const bf16x8*)(qbase);
    bf16x8 aq1 = *(const bf16x8*)(qbase + 32);

    const unsigned short* kB = ks + (size_t)bb * 1024 * 64;
    const unsigned short* vB = vT + (size_t)bb * 64 * 1024;

    f32x4 o[4];
#pragma unroll
    for (int i = 0; i < 4; ++i) o[i] = (f32x4){0.f, 0.f, 0.f, 0.f};
    float psum[4] = {0.f, 0.f, 0.f, 0.f};
    const f32x4 zero = {0.f, 0.f, 0.f, 0.f};

    bf16x8 kc0, kc1, kc2, kc3, vc0, vc1, vc2, vc3;
    if (c0 < c1) {
        const unsigned short* kp = kB + (size_t)(c0 * 32 + c) * 64 + g * 8;
        kc0 = *(const bf16x8*)(kp);
        kc1 = *(const bf16x8*)(kp + 32);
        kc2 = *(const bf16x8*)(kp + 16 * 64);
        kc3 = *(const bf16x8*)(kp + 16 * 64 + 32);
        const unsigned short* vp = vB + (size_t)c * 1024 + c0 * 32 + g * 8;
        vc0 = *(const bf16x8*)(vp);
        vc1 = *(const bf16x8*)(vp + 16 * 1024);
        vc2 = *(const bf16x8*)(vp + 32 * 1024);
        vc3 = *(const bf16x8*)(vp + 48 * 1024);
    }

    for (int ci = c0; ci < c1; ++ci) {
        const int j0 = ci * 32;
        const bool full = (j0 + 16 < qend);
        f32x4 s0 = __builtin_amdgcn_mfma_f32_16x16x32_bf16(aq0, kc0, zero, 0, 0, 0);
        s0 = __builtin_amdgcn_mfma_f32_16x16x32_bf16(aq1, kc1, s0, 0, 0, 0);
        f32x4 s1 = zero;
        if (full) {
            s1 = __builtin_amdgcn_mfma_f32_16x16x32_bf16(aq0, kc2, zero, 0, 0, 0);
            s1 = __builtin_amdgcn_mfma_f32_16x16x32_bf16(aq1, kc3, s1, 0, 0, 0);
        }

        bf16x8 kn0, kn1, kn2, kn3, vn0, vn1, vn2, vn3;
        if (ci + 1 < c1) {
            const int jn = (ci + 1) * 32;
            const unsigned short* kp = kB + (size_t)(jn + c) * 64 + g * 8;
            kn0 = *(const bf16x8*)(kp);
            kn1 = *(const bf16x8*)(kp + 32);
            kn2 = *(const bf16x8*)(kp + 16 * 64);
            kn3 = *(const bf16x8*)(kp + 16 * 64 + 32);
            const unsigned short* vp = vB + (size_t)c * 1024 + jn + g * 8;
            vn0 = *(const bf16x8*)(vp);
            vn1 = *(const bf16x8*)(vp + 16 * 1024);
            vn2 = *(const bf16x8*)(vp + 32 * 1024);
            vn3 = *(const bf16x8*)(vp + 48 * 1024);
        }

#pragma unroll
        for (int r = 0; r < 4; ++r) {
            int t = qr0 + g * 4 + r;
            float e0 = (j0 + c > t) ? 0.f : exp2f(s0[r]);
            float e1 = (!full || j0 + 16 + c > t) ? 0.f : exp2f(s1[r]);
            psum[r] += e0 + e1;
            Plds[wid][(g * 4 + r) * 40 + c]      = f2bf(e0);
            Plds[wid][(g * 4 + r) * 40 + 16 + c] = f2bf(e1);
        }
        bf16x8 pa = *(const bf16x8*)(&Plds[wid][c * 40 + g * 8]);
        o[0] = __builtin_amdgcn_mfma_f32_16x16x32_bf16(pa, vc0, o[0], 0, 0, 0);
        o[1] = __builtin_amdgcn_mfma_f32_16x16x32_bf16(pa, vc1, o[1], 0, 0, 0);
        o[2] = __builtin_amdgcn_mfma_f32_16x16x32_bf16(pa, vc2, o[2], 0, 0, 0);
        o[3] = __builtin_amdgcn_mfma_f32_16x16x32_bf16(pa, vc3, o[3], 0, 0, 0);

        kc0 = kn0; kc1 = kn1; kc2 = kn2; kc3 = kn3;
        vc0 = vn0; vc1 = vn1; vc2 = vn2; vc3 = vn3;
    }

    if (half == 1) {
#pragma unroll
        for (int hb = 0; hb < 4; ++hb)
            *(f32x4*)&oL[tslot][(hb * 64 + lane) * 4] = o[hb];
        f32x4 pv = {psum[0], psum[1], psum[2], psum[3]};
        *(f32x4*)&pL[tslot][lane * 4] = pv;
    }
    __syncthreads();
    if (half == 0) {
        f32x4 pv = *(const f32x4*)&pL[tslot][lane * 4];
        float inv[4];
#pragma unroll
        for (int r = 0; r < 4; ++r) {
            float ps = psum[r] + pv[r];
            ps += __shfl_xor(ps, 1);
            ps += __shfl_xor(ps, 2);
            ps += __shfl_xor(ps, 4);
            ps += __shfl_xor(ps, 8);
            inv[r] = 1.f / ps;
        }
#pragma unroll
        for (int hb = 0; hb < 4; ++hb) {
            f32x4 po = *(const f32x4*)&oL[tslot][(hb * 64 + lane) * 4];
#pragma unroll
            for (int r = 0; r < 4; ++r) {
                int row = g * 4 + r;
                int colb = (hb * 16 + c) * 2;
                *(unsigned short*)((char*)hl[tslot] + row * 128 + (colb ^ ((row & 7) << 4))) =
                    f2bf((o[hb][r] + po[r]) * inv[r]);
            }
        }
    }
    __syncthreads();

    // projection: four 16x64 tiles @ WpEff; wave owns 8 col-blocks; wb loaded once per CB
    // serves all 4 tiles. Unswapped D layout + scalar stores (proven best).
    bf16x8 a0t[4], a1t[4];
#pragma unroll
    for (int t = 0; t < 4; ++t) {
        a0t[t] = *(const bf16x8*)((char*)hl[t] + c * 128 + ((g * 16) ^ ((c & 7) << 4)));
        a1t[t] = *(const bf16x8*)((char*)hl[t] + c * 128 + ((64 + g * 16) ^ ((c & 7) << 4)));
    }
    size_t obase[4];
#pragma unroll
    for (int t = 0; t < 4; ++t) {
        int bt = 2 * xcd + (t & 1);
        int qx = (t >> 1) == 0 ? (63 - k) : k;
        obase[t] = ((size_t)bt * 1024 + qx * 16) * 1024;
    }
#pragma unroll
    for (int cb = 0; cb < 8; ++cb) {
        int CB = wid * 8 + cb;
        bf16x8 wb0 = *(const bf16x8*)(WpFrag + (size_t)(CB * 2 + 0) * 512 + lane * 8);
        bf16x8 wb1 = *(const bf16x8*)(WpFrag + (size_t)(CB * 2 + 1) * 512 + lane * 8);
        int col = CB * 16 + c;
        float bias = bp[col];
#pragma unroll
        for (int t = 0; t < 4; ++t) {
            f32x4 acc = __builtin_amdgcn_mfma_f32_16x16x32_bf16(a0t[t], wb0, zero, 0, 0, 0);
            acc = __builtin_amdgcn_mfma_f32_16x16x32_bf16(a1t[t], wb1, acc, 0, 0, 0);
#pragma unroll
            for (int r = 0; r < 4; ++r) {
                out[obase[t] + (size_t)(g * 4 + r) * 1024 + col] = acc[r] + bias;
            }
        }
    }
}

extern "C" void kernel_launch(void* const* d_in, const int* in_sizes, int n_in,
                              void* d_out, int out_size, void* d_ws, size_t ws_size,
                              hipStream_t stream) {
    (void)in_sizes; (void)n_in; (void)out_size; (void)ws_size;
    const float* x  = (const float*)d_in[0];
    const float* Wq = (const float*)d_in[1];
    const float* Wk = (const float*)d_in[2];
    const float* Wv = (const float*)d_in[3];
    const float* Wp = (const float*)d_in[4];
    const float* bp = (const float*)d_in[5];
    float* out = (float*)d_out;

    const size_t NTOK = 16 * 1024;            // B*T
    unsigned short* ws = (unsigned short*)d_ws;
    unsigned short* qs     = ws;                       // [16384][64]
    unsigned short* ks     = qs + NTOK * 64;           // [16384][64]
    unsigned short* vT     = ks + NTOK * 64;           // [16][64][1024]
    unsigned short* Wfrag  = vT + NTOK * 64;           // [12][32][512]
    unsigned short* WpFrag = Wfrag + 192 * 1024;       // [64][2][512]

    prep_weights<<<128, 256, 0, stream>>>(Wq, Wk, Wv, Wp, Wfrag, WpFrag);
    qkv_gemm<<<512, 256, 0, stream>>>(x, Wfrag, qs, ks, vT);
    attn_proj<<<256, 512, 0, stream>>>(qs, ks, vT, WpFrag, bp, out);
}

// Round 19
// 55.850 us; speedup vs baseline: 1.0783x; 1.0051x over previous
//
#include <hip/hip_runtime.h>
#include <hip/hip_bf16.h>
#include <cstddef>

typedef __attribute__((ext_vector_type(8))) __bf16 bf16x8;
typedef __attribute__((ext_vector_type(4))) float f32x4;
typedef unsigned long long ull_t;

static __device__ __forceinline__ unsigned short f2bf(float f) {
    __bf16 h = (__bf16)f;
    return __builtin_bit_cast(unsigned short, h);
}

// ---------------- prep (merged, coalesced): Wqkv + WpEff in MFMA-fragment order ----------
__global__ void prep_weights(const float* __restrict__ Wq, const float* __restrict__ Wk,
                             const float* __restrict__ Wv, const float* __restrict__ Wp,
                             unsigned short* __restrict__ Wfrag,
                             unsigned short* __restrict__ WpFrag) {
    if (blockIdx.x < 96) {
        int gid = blockIdx.x * 256 + threadIdx.x;    // 0..24575
        int m = gid >> 13;                           // 0..2
        int rem = gid & 8191;
        int khi = rem >> 6;                          // 0..127
        int lcol = rem & 63;                         // 0..63
        const float* W = (m == 0) ? Wq : (m == 1) ? Wk : Wv;
        bf16x8 v;
#pragma unroll
        for (int j = 0; j < 8; ++j)
            v[j] = (__bf16)W[(khi * 8 + j) * 64 + lcol];
        int CB = m * 4 + (lcol >> 4);
        int S = khi >> 2;
        int lane = ((khi & 3) << 4) | (lcol & 15);
        *(bf16x8*)(Wfrag + ((size_t)(CB * 32 + S) * 512 + lane * 8)) = v;
    } else {
        int gid = (blockIdx.x - 96) * 256 + threadIdx.x;    // 0..8191
        int h = gid >> 7;                                   // 0..63
        int cc = gid & 127;                                 // col chunk
        float s0 = 0.f, s1 = 0.f, s2 = 0.f, s3 = 0.f, s4 = 0.f, s5 = 0.f, s6 = 0.f, s7 = 0.f;
#pragma unroll
        for (int j16 = 0; j16 < 16; ++j16) {
            const float* row = Wp + (size_t)(j16 * 64 + h) * 1024 + cc * 8;
            float4 a = *(const float4*)(row);
            float4 b = *(const float4*)(row + 4);
            s0 += a.x; s1 += a.y; s2 += a.z; s3 += a.w;
            s4 += b.x; s5 += b.y; s6 += b.z; s7 += b.w;
        }
        float sum[8] = {s0, s1, s2, s3, s4, s5, s6, s7};
        int sp = h >> 5, hi = (h >> 3) & 3, j = h & 7;
#pragma unroll
        for (int q = 0; q < 8; ++q) {
            int col = cc * 8 + q;
            int lane = (hi << 4) | (col & 15);
            int CB = col >> 4;
            WpFrag[(size_t)(CB * 2 + sp) * 512 + lane * 8 + j] = f2bf(sum[q]);
        }
    }
}

// ---------------- QKV GEMM v11 (R16 best): XCD-aligned producer mapping ------------------
// Block i (XCD = i&7) produces rows of batches {2*(i&7), 2*(i&7)+1} — the SAME batches
// attn_proj consumes on that XCD. K/V/q stay in the producing XCD's L2.
__global__ __launch_bounds__(256) void qkv_gemm(const float* __restrict__ x,
                                                const unsigned short* __restrict__ Wfrag,
                                                unsigned short* __restrict__ qs,
                                                unsigned short* __restrict__ ks,
                                                unsigned short* __restrict__ vT) {
    __shared__ __align__(16) unsigned short xl[2][32 * 128];   // 16 KB, XOR-swizzled rows

    const int tid = threadIdx.x;
    const int lane = tid & 63;
    const int w = tid >> 6;
    const int g = lane >> 4, c = lane & 15;
    const int xcd8 = blockIdx.x & 7;
    const int seq = blockIdx.x >> 3;      // 0..63
    const int row0 = (2 * xcd8 + (seq >> 5)) * 1024 + (seq & 31) * 32;

    const int srow = tid >> 3;            // 0..31
    const int scolf = (tid & 7) * 16;     // float col 0,16,...,112
    const float* xsrc = x + (size_t)(row0 + srow) * 1024 + scolf;
    const int sdst0 = srow * 256 + ((scolf * 2) ^ ((srow & 7) << 4));
    const int sdst1 = srow * 256 + ((scolf * 2 + 16) ^ ((srow & 7) << 4));

    const unsigned short* wbase = Wfrag + (size_t)(w * 3) * 32 * 512 + lane * 8;

    f32x4 acc[2][3];
#pragma unroll
    for (int mr = 0; mr < 2; ++mr)
#pragma unroll
        for (int cb = 0; cb < 3; ++cb) acc[mr][cb] = (f32x4){0.f, 0.f, 0.f, 0.f};

    float4 pre0[4], pre1[4];              // two in-flight x-chunk register sets
#pragma unroll
    for (int i = 0; i < 4; ++i) pre0[i] = *(const float4*)(xsrc + i * 4);
#pragma unroll
    for (int i = 0; i < 4; ++i) pre1[i] = *(const float4*)(xsrc + 128 + i * 4);

    bf16x8 bP[3][6];                      // B pair triple-buffer (i = sl*3+cb)
#pragma unroll
    for (int pp = 0; pp < 2; ++pp) {
#pragma unroll
        for (int i = 0; i < 6; ++i) {
            int SB = pp * 2 + (i / 3);
            int cb = i % 3;
            bP[pp][i] = *(const bf16x8*)(wbase + ((size_t)(cb * 32 + SB) * 512));
        }
    }

    {   // write x chunk 0 to LDS[0]
        bf16x8 v0, v1;
#pragma unroll
        for (int j = 0; j < 4; ++j) { v0[j] = (__bf16)pre0[0][j]; v0[4 + j] = (__bf16)pre0[1][j]; }
#pragma unroll
        for (int j = 0; j < 4; ++j) { v1[j] = (__bf16)pre0[2][j]; v1[4 + j] = (__bf16)pre0[3][j]; }
        *(bf16x8*)((char*)xl[0] + sdst0) = v0;
        *(bf16x8*)((char*)xl[0] + sdst1) = v1;
    }
    __syncthreads();

#pragma unroll
    for (int p = 0; p < 16; ++p) {        // p = k-step pair; chunk t = p>>1 in LDS[t&1]
        const int t = p >> 1;
        if ((p & 1) == 0 && t + 2 < 8) {  // issue x chunk t+2 into set (t&1)
            if ((t & 1) == 0) {
#pragma unroll
                for (int i = 0; i < 4; ++i) pre0[i] = *(const float4*)(xsrc + (t + 2) * 128 + i * 4);
            } else {
#pragma unroll
                for (int i = 0; i < 4; ++i) pre1[i] = *(const float4*)(xsrc + (t + 2) * 128 + i * 4);
            }
        }
        if (p + 2 < 16) {                 // issue B pair p+2 (distance-2)
#pragma unroll
            for (int i = 0; i < 6; ++i) {
                int SB = (p + 2) * 2 + (i / 3);
                int cb = i % 3;
                bP[(p + 2) % 3][i] = *(const bf16x8*)(wbase + ((size_t)(cb * 32 + SB) * 512));
            }
        }
#pragma unroll
        for (int sl = 0; sl < 2; ++sl) {
            int s = (p & 1) * 2 + sl;
            bf16x8 af[2];
#pragma unroll
            for (int mr = 0; mr < 2; ++mr)
                af[mr] = *(const bf16x8*)((char*)xl[t & 1] + (mr * 16 + c) * 256 +
                                          ((s * 64 + g * 16) ^ ((c & 7) << 4)));
#pragma unroll
            for (int cb = 0; cb < 3; ++cb) {
                acc[0][cb] = __builtin_amdgcn_mfma_f32_16x16x32_bf16(af[0], bP[p % 3][sl * 3 + cb], acc[0][cb], 0, 0, 0);
                acc[1][cb] = __builtin_amdgcn_mfma_f32_16x16x32_bf16(af[1], bP[p % 3][sl * 3 + cb], acc[1][cb], 0, 0, 0);
            }
        }
        if (p & 1) {
            if (t < 7) {                  // write x chunk t+1 from set (t+1)&1
                bf16x8 v0, v1;
                if ((t & 1) == 0) {
#pragma unroll
                    for (int j = 0; j < 4; ++j) { v0[j] = (__bf16)pre1[0][j]; v0[4 + j] = (__bf16)pre1[1][j]; }
#pragma unroll
                    for (int j = 0; j < 4; ++j) { v1[j] = (__bf16)pre1[2][j]; v1[4 + j] = (__bf16)pre1[3][j]; }
                    *(bf16x8*)((char*)xl[1] + sdst0) = v0;
                    *(bf16x8*)((char*)xl[1] + sdst1) = v1;
                } else {
#pragma unroll
                    for (int j = 0; j < 4; ++j) { v0[j] = (__bf16)pre0[0][j]; v0[4 + j] = (__bf16)pre0[1][j]; }
#pragma unroll
                    for (int j = 0; j < 4; ++j) { v1[j] = (__bf16)pre0[2][j]; v1[4 + j] = (__bf16)pre0[3][j]; }
                    *(bf16x8*)((char*)xl[0] + sdst0) = v0;
                    *(bf16x8*)((char*)xl[0] + sdst1) = v1;
                }
            }
            __syncthreads();
        }
    }

    const float QSCALE = 0.125f * 1.44269504088896340736f;  // (1/sqrt(64)) * log2(e)
#pragma unroll
    for (int mr = 0; mr < 2; ++mr) {
#pragma unroll
        for (int cb = 0; cb < 3; ++cb) {
            int col = w * 48 + cb * 16 + c;
            int rowb = row0 + mr * 16 + g * 4;
            if (col < 64) {
#pragma unroll
                for (int r = 0; r < 4; ++r)
                    qs[(size_t)(rowb + r) * 64 + col] = f2bf(acc[mr][cb][r] * QSCALE);
            } else if (col < 128) {
#pragma unroll
                for (int r = 0; r < 4; ++r)
                    ks[(size_t)(rowb + r) * 64 + (col - 64)] = f2bf(acc[mr][cb][r]);
            } else {
                int h = col - 128;
                int bb = rowb >> 10, trow = rowb & 1023;
                ull_t dv =
                    (ull_t)f2bf(acc[mr][cb][0]) |
                    ((ull_t)f2bf(acc[mr][cb][1]) << 16) |
                    ((ull_t)f2bf(acc[mr][cb][2]) << 32) |
                    ((ull_t)f2bf(acc[mr][cb][3]) << 48);
                *(ull_t*)(vT + (size_t)bb * 65536 + (size_t)h * 1024 + trow) = dv;
            }
        }
    }
}

// ---------------- fused attention+projection v6 (R16 best) -------------------------------
// xcd = blockIdx&7: each XCD owns batches {2*xcd, 2*xcd+1} (matches qkv producer map).
// 2 tiles/block x 2-wave KV split, linear combine (no max tracking), proj with shared
// WpFrag loads and unswapped scalar stores.
__global__ __launch_bounds__(256) void attn_proj(const unsigned short* __restrict__ qs,
                                                 const unsigned short* __restrict__ ks,
                                                 const unsigned short* __restrict__ vT,
                                                 const unsigned short* __restrict__ WpFrag,
                                                 const float* __restrict__ bp,
                                                 float* __restrict__ out) {
    __shared__ unsigned short Plds[4][16 * 40];
    __shared__ float oL[2][1024];                    // half-1 partial o per tile
    __shared__ float pL[2][256];                     // half-1 partial psum per tile
    __shared__ __align__(16) unsigned short hl[2][16 * 64];   // normalized ho tiles, swizzled

    const int tid = threadIdx.x;
    const int lane = tid & 63;
    const int wid = tid >> 6;
    const int tslot = wid >> 1;       // tile slot 0/1
    const int half = wid & 1;
    const int g = lane >> 4, c = lane & 15;

    const int xcd = blockIdx.x & 7;
    const int k8 = blockIdx.x >> 3;              // 0..63
    const int bb = 2 * xcd + tslot;              // XCD-local batch
    const int qidx = 63 - k8;                    // biggest tiles first per XCD
    const int qr0 = qidx * 16;
    const int qend = qr0 + 16;
    const int nc = (qidx >> 1) + 1;              // KV chunks of 32
    const int c0 = half ? (nc >> 1) : 0;
    const int c1 = half ? nc : (nc >> 1);

    const unsigned short* qbase = qs + ((size_t)bb * 1024 + qr0 + c) * 64 + g * 8;
    bf16x8 aq0 = *(const bf16x8*)(qbase);
    bf16x8 aq1 = *(const bf16x8*)(qbase + 32);

    const unsigned short* kB = ks + (size_t)bb * 1024 * 64;
    const unsigned short* vB = vT + (size_t)bb * 64 * 1024;

    f32x4 o[4];
#pragma unroll
    for (int i = 0; i < 4; ++i) o[i] = (f32x4){0.f, 0.f, 0.f, 0.f};
    float psum[4] = {0.f, 0.f, 0.f, 0.f};
    const f32x4 zero = {0.f, 0.f, 0.f, 0.f};

    bf16x8 kc0, kc1, kc2, kc3, vc0, vc1, vc2, vc3;
    if (c0 < c1) {
        const unsigned short* kp = kB + (size_t)(c0 * 32 + c) * 64 + g * 8;
        kc0 = *(const bf16x8*)(kp);
        kc1 = *(const bf16x8*)(kp + 32);
        kc2 = *(const bf16x8*)(kp + 16 * 64);
        kc3 = *(const bf16x8*)(kp + 16 * 64 + 32);
        const unsigned short* vp = vB + (size_t)c * 1024 + c0 * 32 + g * 8;
        vc0 = *(const bf16x8*)(vp);
        vc1 = *(const bf16x8*)(vp + 16 * 1024);
        vc2 = *(const bf16x8*)(vp + 32 * 1024);
        vc3 = *(const bf16x8*)(vp + 48 * 1024);
    }

    for (int ci = c0; ci < c1; ++ci) {
        const int j0 = ci * 32;
        const bool full = (j0 + 16 < qend);
        f32x4 s0 = __builtin_amdgcn_mfma_f32_16x16x32_bf16(aq0, kc0, zero, 0, 0, 0);
        s0 = __builtin_amdgcn_mfma_f32_16x16x32_bf16(aq1, kc1, s0, 0, 0, 0);
        f32x4 s1 = zero;
        if (full) {
            s1 = __builtin_amdgcn_mfma_f32_16x16x32_bf16(aq0, kc2, zero, 0, 0, 0);
            s1 = __builtin_amdgcn_mfma_f32_16x16x32_bf16(aq1, kc3, s1, 0, 0, 0);
        }

        bf16x8 kn0, kn1, kn2, kn3, vn0, vn1, vn2, vn3;
        if (ci + 1 < c1) {
            const int jn = (ci + 1) * 32;
            const unsigned short* kp = kB + (size_t)(jn + c) * 64 + g * 8;
            kn0 = *(const bf16x8*)(kp);
            kn1 = *(const bf16x8*)(kp + 32);
            kn2 = *(const bf16x8*)(kp + 16 * 64);
            kn3 = *(const bf16x8*)(kp + 16 * 64 + 32);
            const unsigned short* vp = vB + (size_t)c * 1024 + jn + g * 8;
            vn0 = *(const bf16x8*)(vp);
            vn1 = *(const bf16x8*)(vp + 16 * 1024);
            vn2 = *(const bf16x8*)(vp + 32 * 1024);
            vn3 = *(const bf16x8*)(vp + 48 * 1024);
        }

#pragma unroll
        for (int r = 0; r < 4; ++r) {
            int t = qr0 + g * 4 + r;
            float e0 = (j0 + c > t) ? 0.f : exp2f(s0[r]);
            float e1 = (!full || j0 + 16 + c > t) ? 0.f : exp2f(s1[r]);
            psum[r] += e0 + e1;
            Plds[wid][(g * 4 + r) * 40 + c]      = f2bf(e0);
            Plds[wid][(g * 4 + r) * 40 + 16 + c] = f2bf(e1);
        }
        bf16x8 pa = *(const bf16x8*)(&Plds[wid][c * 40 + g * 8]);
        o[0] = __builtin_amdgcn_mfma_f32_16x16x32_bf16(pa, vc0, o[0], 0, 0, 0);
        o[1] = __builtin_amdgcn_mfma_f32_16x16x32_bf16(pa, vc1, o[1], 0, 0, 0);
        o[2] = __builtin_amdgcn_mfma_f32_16x16x32_bf16(pa, vc2, o[2], 0, 0, 0);
        o[3] = __builtin_amdgcn_mfma_f32_16x16x32_bf16(pa, vc3, o[3], 0, 0, 0);

        kc0 = kn0; kc1 = kn1; kc2 = kn2; kc3 = kn3;
        vc0 = vn0; vc1 = vn1; vc2 = vn2; vc3 = vn3;
    }

    if (half == 1) {
#pragma unroll
        for (int hb = 0; hb < 4; ++hb)
            *(f32x4*)&oL[tslot][(hb * 64 + lane) * 4] = o[hb];
        f32x4 pv = {psum[0], psum[1], psum[2], psum[3]};
        *(f32x4*)&pL[tslot][lane * 4] = pv;
    }
    __syncthreads();
    if (half == 0) {
        f32x4 pv = *(const f32x4*)&pL[tslot][lane * 4];
        float inv[4];
#pragma unroll
        for (int r = 0; r < 4; ++r) {
            float ps = psum[r] + pv[r];
            ps += __shfl_xor(ps, 1);
            ps += __shfl_xor(ps, 2);
            ps += __shfl_xor(ps, 4);
            ps += __shfl_xor(ps, 8);
            inv[r] = 1.f / ps;
        }
#pragma unroll
        for (int hb = 0; hb < 4; ++hb) {
            f32x4 po = *(const f32x4*)&oL[tslot][(hb * 64 + lane) * 4];
#pragma unroll
            for (int r = 0; r < 4; ++r) {
                int row = g * 4 + r;
                int colb = (hb * 16 + c) * 2;
                *(unsigned short*)((char*)hl[tslot] + row * 128 + (colb ^ ((row & 7) << 4))) =
                    f2bf((o[hb][r] + po[r]) * inv[r]);
            }
        }
    }
    __syncthreads();

    // projection: both 16x64 tiles @ WpEff -> out; wave owns 16 col-blocks, B loaded once
    bf16x8 a0t0 = *(const bf16x8*)((char*)hl[0] + c * 128 + ((g * 16) ^ ((c & 7) << 4)));
    bf16x8 a1t0 = *(const bf16x8*)((char*)hl[0] + c * 128 + ((64 + g * 16) ^ ((c & 7) << 4)));
    bf16x8 a0t1 = *(const bf16x8*)((char*)hl[1] + c * 128 + ((g * 16) ^ ((c & 7) << 4)));
    bf16x8 a1t1 = *(const bf16x8*)((char*)hl[1] + c * 128 + ((64 + g * 16) ^ ((c & 7) << 4)));
    const int b0 = 2 * xcd;
    const int b1 = 2 * xcd + 1;
    const size_t obase0 = ((size_t)b0 * 1024 + qr0) * 1024;
    const size_t obase1 = ((size_t)b1 * 1024 + qr0) * 1024;
#pragma unroll
    for (int cb = 0; cb < 16; ++cb) {
        int CB = wid * 16 + cb;
        bf16x8 wb0 = *(const bf16x8*)(WpFrag + (size_t)(CB * 2 + 0) * 512 + lane * 8);
        bf16x8 wb1 = *(const bf16x8*)(WpFrag + (size_t)(CB * 2 + 1) * 512 + lane * 8);
        f32x4 acc0 = __builtin_amdgcn_mfma_f32_16x16x32_bf16(a0t0, wb0, zero, 0, 0, 0);
        acc0 = __builtin_amdgcn_mfma_f32_16x16x32_bf16(a1t0, wb1, acc0, 0, 0, 0);
        f32x4 acc1 = __builtin_amdgcn_mfma_f32_16x16x32_bf16(a0t1, wb0, zero, 0, 0, 0);
        acc1 = __builtin_amdgcn_mfma_f32_16x16x32_bf16(a1t1, wb1, acc1, 0, 0, 0);
        int col = CB * 16 + c;
        float bias = bp[col];
#pragma unroll
        for (int r = 0; r < 4; ++r) {
            out[obase0 + (size_t)(g * 4 + r) * 1024 + col] = acc0[r] + bias;
            out[obase1 + (size_t)(g * 4 + r) * 1024 + col] = acc1[r] + bias;
        }
    }
}

extern "C" void kernel_launch(void* const* d_in, const int* in_sizes, int n_in,
                              void* d_out, int out_size, void* d_ws, size_t ws_size,
                              hipStream_t stream) {
    (void)in_sizes; (void)n_in; (void)out_size; (void)ws_size;
    const float* x  = (const float*)d_in[0];
    const float* Wq = (const float*)d_in[1];
    const float* Wk = (const float*)d_in[2];
    const float* Wv = (const float*)d_in[3];
    const float* Wp = (const float*)d_in[4];
    const float* bp = (const float*)d_in[5];
    float* out = (float*)d_out;

    const size_t NTOK = 16 * 1024;            // B*T
    unsigned short* ws = (unsigned short*)d_ws;
    unsigned short* qs     = ws;                       // [16384][64]
    unsigned short* ks     = qs + NTOK * 64;           // [16384][64]
    unsigned short* vT     = ks + NTOK * 64;           // [16][64][1024]
    unsigned short* Wfrag  = vT + NTOK * 64;           // [12][32][512]
    unsigned short* WpFrag = Wfrag + 192 * 1024;       // [64][2][512]

    prep_weights<<<128, 256, 0, stream>>>(Wq, Wk, Wv, Wp, Wfrag, WpFrag);
    qkv_gemm<<<512, 256, 0, stream>>>(x, Wfrag, qs, ks, vT);
    attn_proj<<<512, 256, 0, stream>>>(qs, ks, vT, WpFrag, bp, out);
}